// Round 1
// baseline (291.909 us; speedup 1.0000x reference)
//
#include <hip/hip_runtime.h>

#define H_ 256
#define W_ 512
#define M_ 100
#define CSTUFF 53
#define CTHING 80
#define N_ 64
#define HW_ (H_ * W_)

// One block = 2 rows of one thing-channel (256 threads, 4 px/thread -> float4 store).
// grid = (H/2, N)
__global__ __launch_bounds__(256) void thing_channels_kernel(
    const float* __restrict__ mask_logits,   // [N, CTHING, M, M]
    const float* __restrict__ sem_seg,       // [1, CSTUFF+CTHING, H, W]
    const float* __restrict__ bbox,          // [N, 4]
    const int*   __restrict__ cls_idx,       // [N]
    float* __restrict__ out)                 // [1, 117, H, W]
{
    const int n  = blockIdx.y;
    const int t  = threadIdx.x;
    const int y  = blockIdx.x * 2 + (t >> 7);
    const int xg = (t & 127) << 2;

    const float b0 = bbox[n * 4 + 0];
    const float b1 = bbox[n * 4 + 1];
    const float b2 = bbox[n * 4 + 2];
    const float b3 = bbox[n * 4 + 3];
    const int cls = cls_idx[n];

    // ---- paste geometry (floor of box) ----
    const float x1bf = floorf(b0), y1bf = floorf(b1);
    const int x1b = (int)x1bf, y1b = (int)y1bf;
    const int x2b = (int)floorf(b2), y2b = (int)floorf(b3);
    const float sy = 100.0f / (float)(y2b - y1b + 1);
    const float sx = 100.0f / (float)(x2b - x1b + 1);
    const int pyend = min(y2b + 1, H_);
    const int pxend = min(x2b + 1, W_);

    // ---- crop geometry (trunc / rint of box) ----
    const int cx1 = (int)b0, cy1 = (int)b1;
    const int cx2 = (int)rintf(b2) + 1;
    const int cy2 = (int)rintf(b3) + 1;

    const float* __restrict__ mask = mask_logits + ((size_t)n * CTHING + (size_t)cls) * (M_ * M_);
    const float* __restrict__ ch   = sem_seg + (size_t)(CSTUFF + cls) * HW_;

    // row-level paste factors
    const bool rowPaste = (y >= y1b) && (y < pyend);
    float my = ((float)y - y1bf + 0.5f) * sy - 0.5f;
    my = fmaxf(my, 0.0f);
    const float my0 = floorf(my);
    const float fy  = my - my0;
    const int iy0 = min((int)my0, M_ - 1);
    const int iy1 = min((int)my0 + 1, M_ - 1);
    const bool rowCrop = (y >= cy1) && (y < cy2);

    float4 res;
    float* rp = (float*)&res;
#pragma unroll
    for (int k = 0; k < 4; ++k) {
        const int x = xg + k;
        float v = 0.0f;
        if (rowPaste && (x >= x1b) && (x < pxend)) {
            float mx = ((float)x - x1bf + 0.5f) * sx - 0.5f;
            mx = fmaxf(mx, 0.0f);
            const float mx0 = floorf(mx);
            const float fx  = mx - mx0;
            const int ix0 = min((int)mx0, M_ - 1);
            const int ix1 = min((int)mx0 + 1, M_ - 1);
            const float m00 = mask[iy0 * M_ + ix0];
            const float m01 = mask[iy0 * M_ + ix1];
            const float m10 = mask[iy1 * M_ + ix0];
            const float m11 = mask[iy1 * M_ + ix1];
            const float top = m00 * (1.0f - fx) + m01 * fx;
            const float bot = m10 * (1.0f - fx) + m11 * fx;
            v = (1.0f - fy) * top + fy * bot;
        }
        if (rowCrop && (x >= cx1) && (x < cx2)) {
            v += ch[y * W_ + x];
        }
        rp[k] = v;
    }

    *reinterpret_cast<float4*>(out + (size_t)(CSTUFF + n) * HW_ + (size_t)y * W_ + xg) = res;
}

extern "C" void kernel_launch(void* const* d_in, const int* in_sizes, int n_in,
                              void* d_out, int out_size, void* d_ws, size_t ws_size,
                              hipStream_t stream) {
    const float* mask_logits = (const float*)d_in[0];
    const float* sem_seg     = (const float*)d_in[1];
    const float* bbox        = (const float*)d_in[2];
    const int*   cls_idx     = (const int*)d_in[3];
    float* out = (float*)d_out;

    // Channels 0..52: contiguous copy of the stuff logits.
    hipMemcpyAsync(out, sem_seg, (size_t)CSTUFF * HW_ * sizeof(float),
                   hipMemcpyDeviceToDevice, stream);

    // Channels 53..116: paste(bilinear mask) + crop(thing sem channel).
    dim3 grid(H_ / 2, N_);
    thing_channels_kernel<<<grid, 256, 0, stream>>>(mask_logits, sem_seg, bbox, cls_idx, out);
}

// Round 2
// 289.519 us; speedup vs baseline: 1.0083x; 1.0083x over previous
//
#include <hip/hip_runtime.h>

#define H_ 256
#define W_ 512
#define M_ 100
#define CSTUFF 53
#define CTHING 80
#define N_ 64
#define HW_ (H_ * W_)

// One fused kernel for all 117 output channels.
// grid = (H/2, 117); block = 256 threads; each thread writes one float4 (4 px).
// Channel c < 53 : pure copy of sem_seg stuff channel (block-uniform branch).
// Channel c >= 53: instance n = c-53, paste(bilinear mask) + crop(thing sem ch).
__global__ __launch_bounds__(256) void panoptic_fused_kernel(
    const float* __restrict__ mask_logits,   // [N, CTHING, M, M]
    const float* __restrict__ sem_seg,       // [1, CSTUFF+CTHING, H, W]
    const float* __restrict__ bbox,          // [N, 4]
    const int*   __restrict__ cls_idx,       // [N]
    float* __restrict__ out)                 // [1, 117, H, W]
{
    const int c  = blockIdx.y;
    const int t  = threadIdx.x;
    const int y  = blockIdx.x * 2 + (t >> 7);
    const int xg = (t & 127) << 2;
    const size_t off = (size_t)c * HW_ + (size_t)y * W_ + xg;

    if (c < CSTUFF) {
        // ---- stuff channels: contiguous copy ----
        const float4 v = *reinterpret_cast<const float4*>(sem_seg + off);
        *reinterpret_cast<float4*>(out + off) = v;
        return;
    }

    const int n = c - CSTUFF;
    const float b0 = bbox[n * 4 + 0];
    const float b1 = bbox[n * 4 + 1];
    const float b2 = bbox[n * 4 + 2];
    const float b3 = bbox[n * 4 + 3];
    const int cls = cls_idx[n];

    // ---- paste geometry (floor of box) ----
    const float x1bf = floorf(b0), y1bf = floorf(b1);
    const int x1b = (int)x1bf, y1b = (int)y1bf;
    const int x2b = (int)floorf(b2), y2b = (int)floorf(b3);
    const float sy = 100.0f / (float)(y2b - y1b + 1);
    const float sx = 100.0f / (float)(x2b - x1b + 1);
    const int pyend = min(y2b + 1, H_);
    const int pxend = min(x2b + 1, W_);

    // ---- crop geometry (trunc / rint of box) ----
    const int cx1 = (int)b0, cy1 = (int)b1;
    const int cx2 = (int)rintf(b2) + 1;
    const int cy2 = (int)rintf(b3) + 1;

    const float* __restrict__ mask = mask_logits + ((size_t)n * CTHING + (size_t)cls) * (M_ * M_);
    const float* __restrict__ ch   = sem_seg + (size_t)(CSTUFF + cls) * HW_;

    // row-level paste factors
    const bool rowPaste = (y >= y1b) && (y < pyend);
    float my = ((float)y - y1bf + 0.5f) * sy - 0.5f;
    my = fmaxf(my, 0.0f);
    const float my0 = floorf(my);
    const float fy  = my - my0;
    const int iy0 = min((int)my0, M_ - 1);
    const int iy1 = min((int)my0 + 1, M_ - 1);
    const bool rowCrop = (y >= cy1) && (y < cy2);

    float4 res;
    float* rp = (float*)&res;
#pragma unroll
    for (int k = 0; k < 4; ++k) {
        const int x = xg + k;
        float v = 0.0f;
        if (rowPaste && (x >= x1b) && (x < pxend)) {
            float mx = ((float)x - x1bf + 0.5f) * sx - 0.5f;
            mx = fmaxf(mx, 0.0f);
            const float mx0 = floorf(mx);
            const float fx  = mx - mx0;
            const int ix0 = min((int)mx0, M_ - 1);
            const int ix1 = min((int)mx0 + 1, M_ - 1);
            const float m00 = mask[iy0 * M_ + ix0];
            const float m01 = mask[iy0 * M_ + ix1];
            const float m10 = mask[iy1 * M_ + ix0];
            const float m11 = mask[iy1 * M_ + ix1];
            const float top = m00 * (1.0f - fx) + m01 * fx;
            const float bot = m10 * (1.0f - fx) + m11 * fx;
            v = (1.0f - fy) * top + fy * bot;
        }
        if (rowCrop && (x >= cx1) && (x < cx2)) {
            v += ch[y * W_ + x];
        }
        rp[k] = v;
    }

    *reinterpret_cast<float4*>(out + off) = res;
}

extern "C" void kernel_launch(void* const* d_in, const int* in_sizes, int n_in,
                              void* d_out, int out_size, void* d_ws, size_t ws_size,
                              hipStream_t stream) {
    const float* mask_logits = (const float*)d_in[0];
    const float* sem_seg     = (const float*)d_in[1];
    const float* bbox        = (const float*)d_in[2];
    const int*   cls_idx     = (const int*)d_in[3];
    float* out = (float*)d_out;

    dim3 grid(H_ / 2, CSTUFF + N_);
    panoptic_fused_kernel<<<grid, 256, 0, stream>>>(mask_logits, sem_seg, bbox, cls_idx, out);
}